// Round 12
// baseline (184.686 us; speedup 1.0000x reference)
//
#include <hip/hip_runtime.h>
#include <math.h>

#define NB 10
#define H 512
#define W 512
#define OH 507
#define OW 507
#define TW 32           // output tile width
#define TH 16           // output tile height
#define HC (TW + 7)     // 39 hist cols  (ox0-1 .. ox0+TW+6)
#define HR (TH + 7)     // 23 hist rows
#define IC (TW + 9)     // 41 input cols (ox0-2 .. ox0+TW+7)
#define IR (TH + 9)     // 25 input rows
#define BD 512          // 8 waves/block, 4 blocks/CU -> 32 waves/CU

// numpy float32 remainder (np.mod): fmod then sign-fix, each op exact IEEE f32.
__device__ __forceinline__ float f32mod10(float a) {
    float r = fmodf(a, 10.0f);
    if (r < 0.0f) r = __fadd_rn(r, 10.0f);
    return r;
}

__global__ __launch_bounds__(BD, 8)
void hog_fused(const float* __restrict__ x, float* __restrict__ out) {
    __shared__ __align__(16) float xin[IR][IC];      // 1025 f
    __shared__ __align__(16) float hist[NB][HR][HC]; // 8970 f
    // total 9995 f = 39,980 B -> 4 blocks/CU, 512 thr each = 2048 thr/CU

    const int tid = threadIdx.x;
    const int ox0 = blockIdx.x * TW;
    const int oy0 = blockIdx.y * TH;
    const int n   = blockIdx.z;
    const float* __restrict__ xp = x + (size_t)n * (H * W);

    // ---- zero hist (vectorized) ----
    float* hflat = &hist[0][0][0];
    {
        float4* h4 = (float4*)hflat;                 // 8970 = 2242*4 + 2
        for (int i = tid; i < 2242; i += BD) h4[i] = make_float4(0.f, 0.f, 0.f, 0.f);
        if (tid < 2) hflat[8968 + tid] = 0.0f;
    }

    // ---- load input tile with halo (zero padded outside image) ----
    float* xflat = &xin[0][0];
    for (int i = tid; i < IR * IC; i += BD) {
        int r = i / IC, c = i % IC;
        int gy = oy0 - 2 + r, gx = ox0 - 2 + c;
        float v = 0.0f;
        if (gy >= 0 && gy < H && gx >= 0 && gx < W) v = xp[gy * W + gx];
        xflat[i] = v;
    }
    __syncthreads();

    // ---- Sobel + phase + 2-bin scatter into LDS hist (pure stores) ----
    for (int p = tid; p < HR * HC; p += BD) {
        int hr = p / HC, hc = p % HC;
        int hy = oy0 - 1 + hr, hx = ox0 - 1 + hc;
        if (hy < 0 || hy >= H || hx < 0 || hx >= W) continue;  // pool pad: zero
        float a00 = xin[hr][hc],     a01 = xin[hr][hc + 1],     a02 = xin[hr][hc + 2];
        float a10 = xin[hr + 1][hc],                            a12 = xin[hr + 1][hc + 2];
        float a20 = xin[hr + 2][hc], a21 = xin[hr + 2][hc + 1], a22 = xin[hr + 2][hc + 2];

        // exact numpy-order f32 conv (no contraction) — proven in round 3
        float gxv = __fadd_rn(a00, -a02);
        gxv = __fadd_rn(gxv, __fmul_rn(2.0f, a10));
        gxv = __fadd_rn(gxv, -__fmul_rn(2.0f, a12));
        gxv = __fadd_rn(gxv, a20);
        gxv = __fadd_rn(gxv, -a22);
        float gyv = __fadd_rn(a00, __fmul_rn(2.0f, a01));
        gyv = __fadd_rn(gyv, a02);
        gyv = __fadd_rn(gyv, -a20);
        gyv = __fadd_rn(gyv, -__fmul_rn(2.0f, a21));
        gyv = __fadd_rn(gyv, -a22);

        float ay_ = fabsf(gxv), ax_ = fabsf(gyv);
        float hi = fmaxf(ax_, ay_), lo = fminf(ax_, ay_);
        if (hi == 0.0f) continue;            // atan2(0,0)=0 -> contributes 0
        float nrm = __builtin_amdgcn_sqrtf(
            __fadd_rn(__fmul_rn(gxv, gxv), __fmul_rn(gyv, gyv)));

        // fast f32 atan2(gxv, gyv) * 10/pi, divide-free
        bool exact = (hi < 1e-30f) || (hi > 1e30f);
        float pint = 0.0f;
        if (!exact) {
            float t  = lo * __builtin_amdgcn_rcpf(hi);
            bool red = t > 0.41421356f;
            float u  = red ? (t - 1.0f) * __builtin_amdgcn_rcpf(t + 1.0f) : t;
            float z  = u * u;
            float pl = ((8.05374449538e-2f * z - 1.38776856032e-1f) * z
                        + 1.99777106478e-1f) * z - 3.33329491539e-1f;
            float a  = fmaf(u * z, pl, u);
            if (red) a += 0.78539816339744831f;
            if (ay_ > ax_) a = 1.57079632679489662f - a;
            if (gyv < 0.0f) a = 3.14159265358979324f - a;
            float ph = (gxv < 0.0f) ? -a : a;
            pint = ph * 3.18309886183790672f;
            if (fabsf(pint - rintf(pint)) < 1e-4f) exact = true;
        }

        float b_v, t_v;
        int ib, it;
        if (exact) {
            // bit-exact round-3 chain (matches np f32 reference)
            float phf = (float)atan2((double)gxv, (double)gyv);
            float pe  = __fmul_rn(__fdiv_rn(phf, (float)3.14159265358979323846), 10.0f);
            float bfv = floorf(pe), tfv = ceilf(pe);
            float fm = f32mod10(pe), bm = f32mod10(bfv), tm = f32mod10(tfv);
            t_v = __fmul_rn(nrm, __fsub_rn(1.0f, __fsub_rn(tm, fm)));
            b_v = __fmul_rn(nrm, __fsub_rn(1.0f, __fsub_rn(fm, bm)));
            ib = (((int)bfv % NB) + NB) % NB;
            it = (((int)tfv % NB) + NB) % NB;
        } else {
            // pint in (-10,10), >=1e-4 from any integer. Wrap strips
            // (t-index 0, tm=0) occur exactly when ib==9.
            float bfv  = floorf(pint);
            float frac = pint - bfv;
            float fm   = (pint < 0.0f) ? pint + 10.0f : pint;
            b_v = nrm * (1.0f - frac);
            int bi = (int)bfv;
            ib = (bi < 0) ? bi + 10 : bi;
            if (ib == 9) { it = 0;      t_v = nrm * (1.0f + fm); }
            else         { it = ib + 1; t_v = nrm * frac; }
        }
        // pure stores: cell owned by this thread, pre-zeroed background.
        if (ib == it) {
            hist[ib][hr][hc] = __fadd_rn(b_v, t_v);
        } else {
            hist[ib][hr][hc] = b_v;
            hist[it][hr][hc] = t_v;
        }
    }
    __syncthreads();

    // ---- fused pooling: one wave per bin plane, registers + shuffles ----
    // lane = hist col; vertical 8-row sliding sum in an 8-deep register
    // ring; horizontal 8-sum via 3 shfl_down adds (balanced tree, same
    // order as previous rounds' o0); store straight to global.
    {
        const int wv = tid >> 6;                 // wave id 0..7
        const int ln = tid & 63;
        const int hcc = (ln < HC) ? ln : (HC - 1);   // clamp: broadcast, no conflict
        const int ox  = ox0 + ln;                // output col for this lane
        for (int b = wv; b < NB; b += 8) {       // waves 0,1 take bins 8,9 too
            const float* col = &hist[b][0][hcc];
            float* ob = out + (size_t)(n * NB + b) * OH * OW;
            float ring[8];
            float s = 0.0f;
            #pragma unroll
            for (int hr = 0; hr < HR; ++hr) {
                float v = col[hr * HC];
                s += v;
                if (hr >= 8) s -= ring[hr & 7];
                ring[hr & 7] = v;
                if (hr >= 7) {
                    float t = s;
                    t += __shfl_down(t, 1);
                    t += __shfl_down(t, 2);
                    t += __shfl_down(t, 4);      // sum of s[ln..ln+7]
                    int oy = oy0 + (hr - 7);
                    if (ln < TW && ox < OW && oy < OH)
                        ob[(size_t)oy * OW + ox] = t * (1.0f / 64.0f);
                }
            }
        }
    }
}

extern "C" void kernel_launch(void* const* d_in, const int* in_sizes, int n_in,
                              void* d_out, int out_size, void* d_ws, size_t ws_size,
                              hipStream_t stream) {
    const float* x = (const float*)d_in[0];
    // d_in[1] is the fixed Sobel weight [2,1,3,3]; hard-coded in the kernel.
    float* out = (float*)d_out;
    dim3 grid((OW + TW - 1) / TW, (OH + TH - 1) / TH, 32);
    hog_fused<<<grid, dim3(BD), 0, stream>>>(x, out);
}